// Round 3
// baseline (577.931 us; speedup 1.0000x reference)
//
#include <hip/hip_runtime.h>

// Router_26817775796684 — MI355X/gfx950, round 3.
// conv3x3(SAME)+relu+meanpool+fc+softmax+adaptive-threshold+sigmoid-renorm, fused.
//
// Round-3 changes (vs round 2):
//   * WG = 2 samples (was 4): LDS 29.8 KB -> 4-5 WGs/CU (occupancy 22% -> ~50%).
//     Wave tile M=64 (one sample) x N=64; acc = 16 floatx4 = 64 VGPRs (was 128).
//   * Pair-unrolled barrier-free K loop with explicit b0/b1 register alternation:
//     no bcur<-bnext mov chain (16 VALU/chunk removed); B-load offsets fold to imms.
//   * A layout unchanged: zero-padded 10x10x72ci f16 per sample, 144 B rows;
//     per-chunk shift = single affine byte offset.

typedef _Float16 half8 __attribute__((ext_vector_type(8)));
typedef float    floatx4 __attribute__((ext_vector_type(4)));

#define A_SAMPLE  14400              // 100 rows * 144 B
#define LDS_P_OFF 28800              // pooled[2][128] fp32 after 2 A samples
#define LDS_TOTAL 29824

__global__ void prep_weights(const float* __restrict__ cw, _Float16* __restrict__ Bw) {
  int i = blockIdx.x * 256 + threadIdx.x;   // 0 .. 128*672-1
  int co = i / 672;
  int k  = i - co * 672;
  int s  = k / 72;                          // shift index (9 real, 9 = tail pad)
  int ci = k - s * 72;
  float v = 0.f;
  if (s < 9 && ci < 68) {
    int ky = s / 3, kx = s - 3 * ky;
    v = cw[((co * 68 + ci) * 3 + ky) * 3 + kx];
  }
  Bw[i] = (_Float16)v;                      // pads are EXACT zeros (never NaN)
}

__global__ __launch_bounds__(256, 4) void router_main(
    const float* __restrict__ patch,
    const float* __restrict__ conv_b,
    const _Float16* __restrict__ Bw,
    const float* __restrict__ fc_w,
    const float* __restrict__ fc_b,
    const float* __restrict__ p_wmax,
    const float* __restrict__ p_went,
    const float* __restrict__ p_wgap,
    const float* __restrict__ p_thr,
    const int* __restrict__ p_epoch,
    float* __restrict__ out)
{
  __shared__ __align__(16) unsigned char lds[LDS_TOTAL];
  const int tid    = threadIdx.x;
  const int l      = tid & 63;
  const int w      = tid >> 6;      // wave 0..3
  const int lane15 = l & 15;
  const int quad   = l >> 4;
  const int smp    = w >> 1;        // this wave's sample (0/1)
  const int n0     = (w & 1) * 64;  // N 64-half
  const int n_s    = blockIdx.x * 2;

  // ---- cooperative zero-fill of both padded A regions (borders become zeros) ----
  {
    float4 z4 = make_float4(0.f, 0.f, 0.f, 0.f);
    #pragma unroll
    for (int j = 0; j < 8; ++j) {
      int idx = j * 256 + tid;              // 1800 float4 slots total
      if (idx < 1800) *(float4*)(lds + idx * 16) = z4;
    }
  }
  __syncthreads();
  // ---- waves 0,1 stage sample w interior: lane l = position p=(y,x) ----
  if (w < 2) {
    const float* psrc = patch + (size_t)(n_s + w) * 4352 + l;   // [ci][p] layout
    int y = l >> 3, x = l & 7;
    unsigned char* arow = lds + w * A_SAMPLE + ((y + 1) * 10 + (x + 1)) * 144;
    #pragma unroll
    for (int b = 0; b < 9; ++b) {           // 9 ci-blocks of 8 (68 real + 4 zero pad)
      half8 h;
      #pragma unroll
      for (int j = 0; j < 8; ++j) {
        int ci = b * 8 + j;
        float v = (ci < 68) ? psrc[ci * 64] : 0.f;   // 256 B/wave coalesced
        h[j] = (_Float16)v;
      }
      *(half8*)(arow + b * 16) = h;
    }
  }
  __syncthreads();

  // ---- loop-invariant A fragment base offsets (4 M-tiles of this sample) ----
  int apos[4];
  #pragma unroll
  for (int t = 0; t < 4; ++t) {
    int p  = t * 16 + lane15;                             // position within sample
    int pp = ((p >> 3) + 1) * 10 + (p & 7) + 1;           // padded row
    apos[t] = smp * A_SAMPLE + pp * 144;
  }

  // ---- B gather pointers (per-lane; 172 KB table is L2-resident) ----
  const _Float16* bptr[4];
  #pragma unroll
  for (int n = 0; n < 4; ++n)
    bptr[n] = Bw + (size_t)(n0 + n * 16 + lane15) * 672 + quad * 8;

  floatx4 acc[4][4];
  floatx4 zacc = {0.f, 0.f, 0.f, 0.f};
  #pragma unroll
  for (int t = 0; t < 4; ++t)
    #pragma unroll
    for (int n = 0; n < 4; ++n) acc[t][n] = zacc;

  half8 b0[4], b1[4];
  #pragma unroll
  for (int n = 0; n < 4; ++n) b0[n] = *(const half8*)(bptr[n]);  // chunk 0

  // ---- barrier-free K loop: chunks 0..19 in pairs (b0/b1 alternate, no copies) ----
  #pragma unroll
  for (int cc = 0; cc < 10; ++cc) {
    const int c0 = 2 * cc, c1 = 2 * cc + 1, c2 = 2 * cc + 2;    // c2 <= 20
    #pragma unroll
    for (int n = 0; n < 4; ++n)
      b1[n] = *(const half8*)(bptr[n] + c1 * 32);

    {
      int kb  = c0 * 4 + quad;
      int s   = (kb * 57) >> 9;           // kb/9, exact for 0..83
      int rem = kb - s * 9;
      int dy  = (s * 11) >> 5;            // s/3
      int dx  = s - 3 * dy;
      int roff = (dy * 10 + dx - 11) * 144 + rem * 16;
      half8 afr[4];
      #pragma unroll
      for (int t = 0; t < 4; ++t)
        afr[t] = *(const half8*)(lds + apos[t] + roff);
      #pragma unroll
      for (int t = 0; t < 4; ++t)
        #pragma unroll
        for (int n = 0; n < 4; ++n)
          acc[t][n] = __builtin_amdgcn_mfma_f32_16x16x32_f16(afr[t], b0[n], acc[t][n], 0, 0, 0);
    }

    #pragma unroll
    for (int n = 0; n < 4; ++n)
      b0[n] = *(const half8*)(bptr[n] + c2 * 32);

    {
      int kb  = c1 * 4 + quad;
      int s   = (kb * 57) >> 9;
      int rem = kb - s * 9;
      int dy  = (s * 11) >> 5;
      int dx  = s - 3 * dy;
      int roff = (dy * 10 + dx - 11) * 144 + rem * 16;
      half8 afr[4];
      #pragma unroll
      for (int t = 0; t < 4; ++t)
        afr[t] = *(const half8*)(lds + apos[t] + roff);
      #pragma unroll
      for (int t = 0; t < 4; ++t)
        #pragma unroll
        for (int n = 0; n < 4; ++n)
          acc[t][n] = __builtin_amdgcn_mfma_f32_16x16x32_f16(afr[t], b1[n], acc[t][n], 0, 0, 0);
    }
  }

  // ---- peeled tail chunk c=20 (in b0): kb=80 (quad 0) real; kb 81..83 hit
  //      exact-zero B columns, A offset clamped in-bounds (finite data). ----
  {
    int roff = (quad == 0) ? 1712 : 0;  // kb=80: s=8,rem=8 -> (20+2-11)*144+128
    half8 afr[4];
    #pragma unroll
    for (int t = 0; t < 4; ++t)
      afr[t] = *(const half8*)(lds + apos[t] + roff);
    #pragma unroll
    for (int t = 0; t < 4; ++t)
      #pragma unroll
      for (int n = 0; n < 4; ++n)
        acc[t][n] = __builtin_amdgcn_mfma_f32_16x16x32_f16(afr[t], b0[n], acc[t][n], 0, 0, 0);
  }

  // ---- bias + relu + mean-pool (C layout: row = quad*4+reg, col = lane15) ----
  float bcoef[4];
  #pragma unroll
  for (int n = 0; n < 4; ++n) bcoef[n] = conv_b[n0 + n * 16 + lane15];

  float* pl = (float*)(lds + LDS_P_OFF);          // pooled[2][128]
  #pragma unroll
  for (int n = 0; n < 4; ++n) {
    float ssum = 0.f;
    #pragma unroll
    for (int t = 0; t < 4; ++t)
      #pragma unroll
      for (int r = 0; r < 4; ++r)
        ssum += fmaxf(acc[t][n][r] + bcoef[n], 0.f);
    ssum += __shfl_xor(ssum, 16);                 // sum the 4 quad partials
    ssum += __shfl_xor(ssum, 32);
    if (l < 16)
      pl[smp * 128 + n0 + n * 16 + lane15] = ssum * (1.f / 64.f);
  }
  __syncthreads();

  // ---- fused routing epilogue: waves 0,1 handle samples 0,1 ----
  if (w < 2) {
    const float* plw = pl + w * 128;
    int e  = l >> 3;                                 // expert 0..7
    int c8 = l & 7;
    float part = 0.f;
    #pragma unroll
    for (int m = 0; m < 16; ++m) {
      int co = c8 + 8 * m;
      part += plw[co] * fc_w[co * 8 + e];
    }
    part += __shfl_xor(part, 1);
    part += __shfl_xor(part, 2);
    part += __shfl_xor(part, 4);

    float lg[8];
    #pragma unroll
    for (int j = 0; j < 8; ++j) lg[j] = __shfl(part, j * 8) + fc_b[j];

    float mx = lg[0];
    #pragma unroll
    for (int j = 1; j < 8; ++j) mx = fmaxf(mx, lg[j]);
    float wgt[8]; float sum = 0.f;
    #pragma unroll
    for (int j = 0; j < 8; ++j) { wgt[j] = expf(lg[j] - mx); sum += wgt[j]; }
    float inv = 1.f / sum;
    #pragma unroll
    for (int j = 0; j < 8; ++j) wgt[j] *= inv;

    // sort descending — Batcher odd-even, 19 comparators
    float sw[8];
    #pragma unroll
    for (int j = 0; j < 8; ++j) sw[j] = wgt[j];
    #define CSD(i, j) { float hi_ = fmaxf(sw[i], sw[j]); float lo_ = fminf(sw[i], sw[j]); sw[i] = hi_; sw[j] = lo_; }
    CSD(0,1) CSD(2,3) CSD(4,5) CSD(6,7)
    CSD(0,2) CSD(1,3) CSD(4,6) CSD(5,7)
    CSD(1,2) CSD(5,6)
    CSD(0,4) CSD(1,5) CSD(2,6) CSD(3,7)
    CSD(2,4) CSD(3,5)
    CSD(1,2) CSD(3,4) CSD(5,6)
    #undef CSD

    float s1 = 0.f;
    #pragma unroll
    for (int j = 0; j < 8; ++j) s1 += wgt[j];
    float mean = s1 * 0.125f;
    float var = 0.f;
    #pragma unroll
    for (int j = 0; j < 8; ++j) { float d = wgt[j] - mean; var += d * d; }
    float stdv = sqrtf(var * (1.f / 7.f));          // ddof=1
    float ent = 0.f;
    #pragma unroll
    for (int j = 0; j < 8; ++j) ent -= wgt[j] * logf(wgt[j] + 1e-18f);

    float maxc  = 1.f - sw[0];
    float entc  = 1.f - ent * 0.48089834696298783f; // 1/log(8)
    float mrest = (sw[1] + sw[2] + sw[3] + sw[4]) * 0.25f;
    float gap   = (sw[0] - mrest) / (sw[0] + 1e-8f);
    gap = fminf(fmaxf(gap, 0.f), 1.f);
    float af = p_wmax[0] * maxc + p_went[0] * entc + p_wgap[0] * gap;
    float th = p_thr[0] * (0.5f + af);
    float mn  = fmaxf(0.05f, mean - 0.5f * stdv);
    float mxt = fminf(0.7f, sw[0] - 0.1f * stdv);
    th = fminf(fmaxf(th, mn), mxt);                 // jnp.clip: lower then upper
    th = fminf(th, sw[1] * 0.9f);                   // kth = sw[MIN_EXPERTS_ACTIVE-1]

    int epoch = p_epoch[0];
    float outv[8];
    if (epoch < 20) {
      #pragma unroll
      for (int j = 0; j < 8; ++j) outv[j] = 0.125f;
    } else {
      float tau = (epoch <= 25) ? fmaxf(0.1f, 1.0f - (float)(epoch - 20) * 0.18f) : 0.1f;
      // forward value of hard + stopgrad(soft-hard) == soft exactly
      float ssum = 0.f;
      #pragma unroll
      for (int j = 0; j < 8; ++j) {
        float sj = 1.f / (1.f + expf(-(wgt[j] - th) / tau));
        outv[j] = sj; ssum += sj;
      }
      float invs = 1.f / fmaxf(ssum, 1e-8f);
      #pragma unroll
      for (int j = 0; j < 8; ++j) outv[j] *= invs;
    }

    if (l < 8) {
      float mv = outv[0];
      #pragma unroll
      for (int j = 1; j < 8; ++j) mv = (l == j) ? outv[j] : mv;
      out[(n_s + w) * 8 + l] = mv;
    }
  }
}

extern "C" void kernel_launch(void* const* d_in, const int* in_sizes, int n_in,
                              void* d_out, int out_size, void* d_ws, size_t ws_size,
                              hipStream_t stream) {
  const float* patch  = (const float*)d_in[0];
  const float* conv_w = (const float*)d_in[1];
  const float* conv_b = (const float*)d_in[2];
  const float* fc_w   = (const float*)d_in[3];
  const float* fc_b   = (const float*)d_in[4];
  const float* wmax   = (const float*)d_in[5];
  const float* went   = (const float*)d_in[6];
  const float* wgap   = (const float*)d_in[7];
  const float* thr    = (const float*)d_in[8];
  const int*   epoch  = (const int*)d_in[10];
  float* outp = (float*)d_out;
  _Float16* Bw = (_Float16*)d_ws;                 // 128*672*2 = 172,032 B of ws

  int N = in_sizes[0] / 4352;                     // 16384 samples
  prep_weights<<<336, 256, 0, stream>>>(conv_w, Bw);
  router_main<<<N / 2, 256, 0, stream>>>(patch, conv_b, Bw, fc_w, fc_b,
                                         wmax, went, wgap, thr, epoch, outp);
}